// Round 9
// baseline (104.462 us; speedup 1.0000x reference)
//
#include <hip/hip_runtime.h>
#include <hip/hip_bf16.h>

#define NSPLIT 16
#define BIGF 1e30f
#define MARGIN 0.3f
#define DK 128

typedef __attribute__((ext_vector_type(8))) short bf16x8;
typedef __attribute__((ext_vector_type(4))) float f32x4;

// workspace word offsets
#define WS_HIST 0                  // 1024 u32 label histogram  (zeroed by prep, filled by tile y==0)
#define WS_GSUM 1024               // f32 sum                   (zeroed by prep)
#define WS_GCNT 1025               // f32 cnt                   (zeroed by prep)
#define WS_BCNT 1026               // u32 block counter         (zeroed by prep)
#define WS_HP   1028               // 8192 u32 max d2_pos bits  (init by prep)
#define WS_HN   (WS_HP + 8192)     // 8192 u32 max ~d2_neg bits (init by prep)
#define WS_SQ   (WS_HN + 8192)     // 8192 f32 squared norms    (written by prep)
#define WS_XB   (WS_SQ + 8192)     // bf16 copy of X, fragment-swizzled (16B aligned)

// Fragment-swizzled bf16 layout of X:
//   xs[ (row>>4)*2048 + (k>>3)*128 + (row&15)*8 + (k&7) ]
// An MFMA A/B fragment load (16 rows, k = s*32+quad*8..+7) is 64 lanes reading
// ONE CONTIGUOUS 1KB block -> coalesced global_load_dwordx4.

// Kernel 1: swizzled bf16 copy + fp32 squared norms + zero-init of hist,
// scalars, and per-row hp/hn atomic slots. (unchanged from round 8)
__global__ __launch_bounds__(256) void prep_kernel(
    const float* __restrict__ x, ushort* __restrict__ xs,
    float* __restrict__ sq, unsigned* __restrict__ hist,
    unsigned* __restrict__ scal,
    unsigned* __restrict__ hp_bits, unsigned* __restrict__ hn_comp, int N)
{
    const int tid = threadIdx.x;
    const int rbase = blockIdx.x * 32;
    const int rl = tid >> 4;           // row within 16-row group (0..15)
    const int kc = tid & 15;           // 8-elem k-chunk (0..15)

    if (tid < 4) {
        hist[blockIdx.x * 4 + tid] = 0u;
        if (blockIdx.x == 0) scal[tid] = 0u;   // gsum, gcnt, bcount, pad
    }

    #pragma unroll
    for (int g = 0; g < 2; ++g) {
        int row = rbase + g * 16 + rl;
        const float4* p = (const float4*)(x + (size_t)row * DK + kc * 8);
        float4 u = p[0], v = p[1];
        float f[8] = {u.x, u.y, u.z, u.w, v.x, v.y, v.z, v.w};
        union { bf16x8 v8; ushort us[8]; } o;
        float ps = 0.0f;
        #pragma unroll
        for (int e = 0; e < 8; ++e) {
            __hip_bfloat16 b = __float2bfloat16(f[e]);
            o.us[e] = *(ushort*)&b;
            ps += f[e] * f[e];
        }
        ((bf16x8*)xs)[(size_t)(row >> 4) * 256 + kc * 16 + rl] = o.v8;
        #pragma unroll
        for (int o2 = 8; o2 > 0; o2 >>= 1) ps += __shfl_xor(ps, o2, 16);
        if (kc == 0) {
            sq[row] = ps;
            hp_bits[row] = 0u;             // identity for max(d2p>=0)
            hn_comp[row] = 0u;             // ~bits identity for min-complement
        }
    }
}

// ---- tile_kernel helpers ------------------------------------------------

// Load one 16-col B chunk: 4 coalesced b128 frag loads + 1 sq + 1 lab.
#define LOADB(B, SQB, LB, CH)                                             \
    {                                                                     \
        const unsigned cb = (unsigned)cbegin + (unsigned)(CH) * 16;       \
        const ushort* bp = xs + (size_t)cb * DK + quad * 128 + m16 * 8;   \
        _Pragma("unroll")                                                 \
        for (int s = 0; s < 4; ++s)                                       \
            B[s] = *(const bf16x8*)(bp + s * 512);                        \
        int colg = (int)cb + m16;                                         \
        SQB = sq[colg]; LB = lab[colg];                                   \
    }

// 16 MFMAs for one 64x16 output chunk; C=0 folded into s=0.
#define MFMA_CHUNK(B)                                                     \
    _Pragma("unroll")                                                     \
    for (int s = 0; s < 4; ++s)                                           \
        _Pragma("unroll")                                                 \
        for (int mt = 0; mt < 4; ++mt)                                    \
            acc[mt] = __builtin_amdgcn_mfma_f32_16x16x32_bf16(            \
                afr[mt][s], B[s],                                         \
                (s == 0) ? (f32x4){0.f, 0.f, 0.f, 0.f} : acc[mt],         \
                0, 0, 0);

// masked max/min epilogue: 16 outputs/lane per chunk.
#define EPI_CHUNK(SQB, LB)                                                \
    _Pragma("unroll")                                                     \
    for (int mt = 0; mt < 4; ++mt)                                        \
        _Pragma("unroll")                                                 \
        for (int r = 0; r < 4; ++r) {                                     \
            float t = fmaf(-2.0f, acc[mt][r], SQB);                       \
            bool sm = (rlv[mt][r] == LB);                                 \
            runhp[mt][r] = fmaxf(runhp[mt][r], sm ? t : -BIGF);           \
            runhn[mt][r] = fminf(runhn[mt][r], sm ? BIGF : t);            \
        }

// Kernel 2: fused bf16-MFMA dist^2 tile + masked max/min in t = sqb - 2*dot.
// TALLER M-TILE: each wave owns 64 rows (afr 64 VGPR, reused 32x) -> per-CU
// B traffic halves (2MB -> 1MB), load instructions halve, and each 16-col
// chunk carries 16 MFMA + 16-output EPI (~240cy) against only 4 b128 loads.
// VGPR ~190: stays in the <=256 band -> 2 waves/SIMD unchanged. Grid (32,16)
// = 512 blocks = one residency generation at 2 blocks/CU (as round 8).
// LDS-free, barrier-free; round-8 schedule (load-next -> MFMA -> EPI).
__global__ __launch_bounds__(256, 2) void tile_kernel(
    const ushort* __restrict__ xs, const float* __restrict__ sq,
    const int* __restrict__ lab, unsigned* __restrict__ hist,
    unsigned* __restrict__ hp_bits, unsigned* __restrict__ hn_comp, int N)
{
    const int tid  = threadIdx.x;
    const int lane = tid & 63;
    const int wave = tid >> 6;
    const int m16  = lane & 15;
    const int quad = lane >> 4;
    const int rbase  = blockIdx.x * 256 + wave * 64;
    const int cbegin = blockIdx.y * (N / NSPLIT);

    // A fragments first: their latency overlaps hist/rlv setup below
    bf16x8 afr[4][4];
    {
        const ushort* ap = xs + (size_t)rbase * DK + quad * 128 + m16 * 8;
        #pragma unroll
        for (int mt = 0; mt < 4; ++mt)
            #pragma unroll
            for (int s = 0; s < 4; ++s)
                afr[mt][s] = *(const bf16x8*)(ap + mt * 2048 + s * 512);
    }

    // label histogram: each block-row counted once, by its y==0 block
    if (blockIdx.y == 0)
        atomicAdd(&hist[lab[blockIdx.x * 256 + tid]], 1u);

    // row labels for this lane's 16 output rows (broadcast int4 loads)
    int rlv[4][4];
    #pragma unroll
    for (int mt = 0; mt < 4; ++mt) {
        int4 v = *(const int4*)(lab + rbase + mt * 16 + quad * 4);
        rlv[mt][0] = v.x; rlv[mt][1] = v.y; rlv[mt][2] = v.z; rlv[mt][3] = v.w;
    }

    float runhp[4][4], runhn[4][4];
    #pragma unroll
    for (int mt = 0; mt < 4; ++mt)
        #pragma unroll
        for (int r = 0; r < 4; ++r) { runhp[mt][r] = -BIGF; runhn[mt][r] = BIGF; }

    bf16x8 bA[4], bB[4];
    float sqA, sqB;
    int lbA, lbB;
    f32x4 acc[4];

    LOADB(bA, sqA, lbA, 0);

    // 32 chunks of 16 cols (512-col split); 2-chunk body, indexing static.
    #pragma unroll 1
    for (int k = 0; k < 32; k += 2) {
        LOADB(bB, sqB, lbB, k + 1);         // in flight under MFMA+EPI of bA
        MFMA_CHUNK(bA);
        EPI_CHUNK(sqA, lbA);
        LOADB(bA, sqA, lbA, (k + 2 < 32) ? k + 2 : 31);  // clamped: dead on last
        MFMA_CHUNK(bB);
        EPI_CHUNK(sqB, lbB);
    }

    // reduce across the 16 m16-lanes (cols) sharing each row
    #pragma unroll
    for (int mt = 0; mt < 4; ++mt)
        #pragma unroll
        for (int r = 0; r < 4; ++r) {
            #pragma unroll
            for (int o = 8; o > 0; o >>= 1) {
                runhp[mt][r] = fmaxf(runhp[mt][r], __shfl_xor(runhp[mt][r], o, 16));
                runhn[mt][r] = fminf(runhn[mt][r], __shfl_xor(runhn[mt][r], o, 16));
            }
        }

    if (m16 == 0) {
        #pragma unroll
        for (int mt = 0; mt < 4; ++mt)
            #pragma unroll
            for (int r = 0; r < 4; ++r) {
                int row = rbase + mt * 16 + quad * 4 + r;
                float sqa = sq[row];
                float d2p = fmaxf(sqa + runhp[mt][r], 0.0f);  // == ref's max(d2,0)
                float d2n = fmaxf(sqa + runhn[mt][r], 0.0f);
                atomicMax(&hp_bits[row], __float_as_uint(d2p));
                atomicMax(&hn_comp[row], ~__float_as_uint(d2n));  // min via complement
            }
    }
}

// Kernel 3: per-row loss + grid reduction; last block writes the scalar.
__global__ void finalize_kernel(const unsigned* __restrict__ hp_bits,
                                const unsigned* __restrict__ hn_comp,
                                const int* __restrict__ lab,
                                const unsigned* __restrict__ hist,
                                float* __restrict__ gsum, float* __restrict__ gcnt,
                                unsigned* __restrict__ bcount,
                                float* __restrict__ out, int N)
{
    __shared__ float s_sum[256];
    __shared__ float s_cnt[256];
    int tid = threadIdx.x;
    int row = blockIdx.x * 256 + tid;
    float loss = 0.0f, cv = 0.0f;
    if (row < N) {
        unsigned c = hist[lab[row]];
        bool valid = (c >= 2u) && (c < (unsigned)N);
        if (valid) {
            float dp = sqrtf(__uint_as_float(hp_bits[row]));
            float dn = sqrtf(__uint_as_float(~hn_comp[row]));
            loss = fmaxf(dp - dn + MARGIN, 0.0f);
            cv = 1.0f;
        }
    }
    s_sum[tid] = loss; s_cnt[tid] = cv;
    __syncthreads();
    for (int o = 128; o > 0; o >>= 1) {
        if (tid < o) { s_sum[tid] += s_sum[tid + o]; s_cnt[tid] += s_cnt[tid + o]; }
        __syncthreads();
    }
    if (tid == 0) {
        atomicAdd(gsum, s_sum[0]);
        atomicAdd(gcnt, s_cnt[0]);
        __threadfence();
        unsigned old = atomicAdd(bcount, 1u);
        if (old == gridDim.x - 1) {
            float s = atomicAdd(gsum, 0.0f);   // coherent read
            float c = atomicAdd(gcnt, 0.0f);
            out[0] = (c > 0.0f) ? s / c : 0.0f;
        }
    }
}

extern "C" void kernel_launch(void* const* d_in, const int* in_sizes, int n_in,
                              void* d_out, int out_size, void* d_ws, size_t ws_size,
                              hipStream_t stream) {
    const float* x = (const float*)d_in[0];
    const int* lab = (const int*)d_in[1];
    float* out = (float*)d_out;
    const int N = in_sizes[1];          // 8192

    unsigned* ws = (unsigned*)d_ws;
    unsigned* hist    = ws + WS_HIST;
    unsigned* scal    = ws + WS_GSUM;   // gsum, gcnt, bcount, pad
    float* gsum = (float*)(ws + WS_GSUM);
    float* gcnt = (float*)(ws + WS_GCNT);
    unsigned* bcount = ws + WS_BCNT;
    unsigned* hp_bits = ws + WS_HP;
    unsigned* hn_comp = ws + WS_HN;
    float* sq = (float*)(ws + WS_SQ);
    ushort* xs = (ushort*)(ws + WS_XB);

    prep_kernel<<<N / 32, 256, 0, stream>>>(x, xs, sq, hist, scal, hp_bits, hn_comp, N);
    dim3 grid(N / 256, NSPLIT);
    tile_kernel<<<grid, 256, 0, stream>>>(xs, sq, lab, hist, hp_bits, hn_comp, N);
    finalize_kernel<<<N / 256, 256, 0, stream>>>(hp_bits, hn_comp, lab, hist,
                                                 gsum, gcnt, bcount, out, N);
}

// Round 10
// 88.376 us; speedup vs baseline: 1.1820x; 1.1820x over previous
//
#include <hip/hip_runtime.h>
#include <hip/hip_bf16.h>

#define NSPLIT 16
#define BIGF 1e30f
#define MARGIN 0.3f
#define DK 128

typedef __attribute__((ext_vector_type(8))) short bf16x8;
typedef __attribute__((ext_vector_type(4))) float f32x4;

// workspace word offsets
#define WS_HIST 0                  // 1024 u32 label histogram  (zeroed by prep, filled by tile y==0)
#define WS_GSUM 1024               // f32 sum                   (zeroed by prep)
#define WS_GCNT 1025               // f32 cnt                   (zeroed by prep)
#define WS_BCNT 1026               // u32 block counter         (zeroed by prep)
#define WS_HP   1028               // 8192 u32 max d2_pos bits  (init by prep)
#define WS_HN   (WS_HP + 8192)     // 8192 u32 max ~d2_neg bits (init by prep)
#define WS_SQ   (WS_HN + 8192)     // 8192 f32 squared norms    (written by prep)
#define WS_XB   (WS_SQ + 8192)     // bf16 copy of X, fragment-swizzled (16B aligned)

// Fragment-swizzled bf16 layout of X:
//   xs[ (row>>4)*2048 + (k>>3)*128 + (row&15)*8 + (k&7) ]
// A fragment load (16 rows, k = s*32+quad*8..+7) is 64 lanes reading ONE
// CONTIGUOUS 1KB block; a 32-col chunk is ONE CONTIGUOUS 8KB region.

// Kernel 1: swizzled bf16 copy + fp32 squared norms + zero-init of hist,
// scalars, and per-row hp/hn atomic slots. (unchanged from round 8)
__global__ __launch_bounds__(256) void prep_kernel(
    const float* __restrict__ x, ushort* __restrict__ xs,
    float* __restrict__ sq, unsigned* __restrict__ hist,
    unsigned* __restrict__ scal,
    unsigned* __restrict__ hp_bits, unsigned* __restrict__ hn_comp, int N)
{
    const int tid = threadIdx.x;
    const int rbase = blockIdx.x * 32;
    const int rl = tid >> 4;           // row within 16-row group (0..15)
    const int kc = tid & 15;           // 8-elem k-chunk (0..15)

    if (tid < 4) {
        hist[blockIdx.x * 4 + tid] = 0u;
        if (blockIdx.x == 0) scal[tid] = 0u;   // gsum, gcnt, bcount, pad
    }

    #pragma unroll
    for (int g = 0; g < 2; ++g) {
        int row = rbase + g * 16 + rl;
        const float4* p = (const float4*)(x + (size_t)row * DK + kc * 8);
        float4 u = p[0], v = p[1];
        float f[8] = {u.x, u.y, u.z, u.w, v.x, v.y, v.z, v.w};
        union { bf16x8 v8; ushort us[8]; } o;
        float ps = 0.0f;
        #pragma unroll
        for (int e = 0; e < 8; ++e) {
            __hip_bfloat16 b = __float2bfloat16(f[e]);
            o.us[e] = *(ushort*)&b;
            ps += f[e] * f[e];
        }
        ((bf16x8*)xs)[(size_t)(row >> 4) * 256 + kc * 16 + rl] = o.v8;
        #pragma unroll
        for (int o2 = 8; o2 > 0; o2 >>= 1) ps += __shfl_xor(ps, o2, 16);
        if (kc == 0) {
            sq[row] = ps;
            hp_bits[row] = 0u;             // identity for max(d2p>=0)
            hn_comp[row] = 0u;             // ~bits identity for min-complement
        }
    }
}

// Kernel 2: fused bf16-MFMA dist^2 tile + masked max/min in t = sqb - 2*dot.
// OCCUPANCY FIX (round-9 counters: 18% occ, VGPR mis-allocation): B moves to
// LDS, shared by the block's 4 waves. B-frags become short transients (8
// regs/s-step) instead of 64 persistent prefetch regs -> working set ~105
// -> 128-VGPR cap holds -> 4 waves/SIMD, 4 blocks/CU (~50% occ), and B
// global traffic per CU drops 4x (one fetch per block, not per wave).
// 2-buffer LDS pipeline, ONE barrier per chunk; reg-staging split (T14):
// issue global loads right after the barrier, ds_write after EPI (~400cy
// cover). Buffer hazards: buf[(k+1)&1] overwrite happens after barrier k;
// its last readers finished before barrier k (program order).  LDS 16KB.
__global__ __launch_bounds__(256, 4) void tile_kernel(
    const ushort* __restrict__ xs, const float* __restrict__ sq,
    const int* __restrict__ lab, unsigned* __restrict__ hist,
    unsigned* __restrict__ hp_bits, unsigned* __restrict__ hn_comp, int N)
{
    __shared__ ushort bs[2][4096];     // 2 x 8KB: one 32-col swizzled chunk each

    const int tid  = threadIdx.x;
    const int lane = tid & 63;
    const int wave = tid >> 6;
    const int m16  = lane & 15;
    const int quad = lane >> 4;
    const int rbase  = blockIdx.x * 128 + wave * 32;
    const int cbegin = blockIdx.y * (N / NSPLIT);
    const int lbase  = quad * 128 + m16 * 8;     // frag offset within a 4KB group

    // label histogram: each block-row counted once, by its y==0 block
    if (blockIdx.y == 0 && tid < 128)
        atomicAdd(&hist[lab[blockIdx.x * 128 + tid]], 1u);

    // A fragments: registers for the whole kernel (reused 16x)
    bf16x8 afr[2][4];
    {
        const ushort* ap = xs + (size_t)rbase * DK + lbase;
        #pragma unroll
        for (int mt = 0; mt < 2; ++mt)
            #pragma unroll
            for (int s = 0; s < 4; ++s)
                afr[mt][s] = *(const bf16x8*)(ap + mt * 2048 + s * 512);
    }

    // row labels for this lane's 8 output rows (broadcast int4 loads)
    int rlv[2][4];
    #pragma unroll
    for (int mt = 0; mt < 2; ++mt) {
        int4 v = *(const int4*)(lab + rbase + mt * 16 + quad * 4);
        rlv[mt][0] = v.x; rlv[mt][1] = v.y; rlv[mt][2] = v.z; rlv[mt][3] = v.w;
    }

    float runhp[2][4], runhn[2][4];
    #pragma unroll
    for (int mt = 0; mt < 2; ++mt)
        #pragma unroll
        for (int r = 0; r < 4; ++r) { runhp[mt][r] = -BIGF; runhn[mt][r] = BIGF; }

    // prologue: stage chunk 0 (each thread copies 2 x 16B units of the 8KB chunk)
    {
        const bf16x8* src = (const bf16x8*)(xs + (size_t)cbegin * DK);
        bf16x8* dst = (bf16x8*)&bs[0][0];
        dst[tid]       = src[tid];
        dst[tid + 256] = src[tid + 256];
    }

    const int NCH = (N / NSPLIT) / 32;             // 16 chunks of 32 cols

    #pragma unroll 1
    for (int k = 0; k < NCH; ++k) {
        const int buf = k & 1;
        __syncthreads();   // staging of bs[buf] complete; prev consume done

        // issue next chunk's global loads NOW (latency hides under MFMA+EPI)
        bf16x8 st0, st1;
        if (k + 1 < NCH) {
            const bf16x8* src = (const bf16x8*)(xs + (size_t)(cbegin + (k + 1) * 32) * DK);
            st0 = src[tid];
            st1 = src[tid + 256];
        }

        // per-chunk col scalars (L1 broadcast; consumed only in EPI)
        const int cb = cbegin + k * 32;
        float sqb0 = sq[cb + m16],      sqb1 = sq[cb + 16 + m16];
        int   lb0  = lab[cb + m16],     lb1  = lab[cb + 16 + m16];

        // MFMA: ds_read frags per s-step (transient 8 regs), C=0 folded at s=0
        f32x4 acc[2][2];
        #pragma unroll
        for (int s = 0; s < 4; ++s) {
            bf16x8 b0 = *(const bf16x8*)&bs[buf][s * 512 + lbase];
            bf16x8 b1 = *(const bf16x8*)&bs[buf][2048 + s * 512 + lbase];
            #pragma unroll
            for (int mt = 0; mt < 2; ++mt) {
                acc[mt][0] = __builtin_amdgcn_mfma_f32_16x16x32_bf16(
                    afr[mt][s], b0,
                    (s == 0) ? (f32x4){0.f, 0.f, 0.f, 0.f} : acc[mt][0], 0, 0, 0);
                acc[mt][1] = __builtin_amdgcn_mfma_f32_16x16x32_bf16(
                    afr[mt][s], b1,
                    (s == 0) ? (f32x4){0.f, 0.f, 0.f, 0.f} : acc[mt][1], 0, 0, 0);
            }
        }

        // masked max/min epilogue (fmaxf(fmaxf) -> v_max3 / v_min3)
        #pragma unroll
        for (int mt = 0; mt < 2; ++mt)
            #pragma unroll
            for (int r = 0; r < 4; ++r) {
                int rl = rlv[mt][r];
                float t0 = fmaf(-2.0f, acc[mt][0][r], sqb0);
                float t1 = fmaf(-2.0f, acc[mt][1][r], sqb1);
                bool s0 = (rl == lb0);
                bool s1 = (rl == lb1);
                runhp[mt][r] = fmaxf(fmaxf(runhp[mt][r], s0 ? t0 : -BIGF),
                                     s1 ? t1 : -BIGF);
                runhn[mt][r] = fminf(fminf(runhn[mt][r], s0 ? BIGF : t0),
                                     s1 ? BIGF : t1);
            }

        // write the staged regs into the other buffer (vmcnt waited here,
        // ~400cy after issue; lgkmcnt drained by next barrier)
        if (k + 1 < NCH) {
            bf16x8* dst = (bf16x8*)&bs[buf ^ 1][0];
            dst[tid]       = st0;
            dst[tid + 256] = st1;
        }
    }

    // reduce across the 16 m16-lanes (cols) sharing each row
    #pragma unroll
    for (int mt = 0; mt < 2; ++mt)
        #pragma unroll
        for (int r = 0; r < 4; ++r) {
            #pragma unroll
            for (int o = 8; o > 0; o >>= 1) {
                runhp[mt][r] = fmaxf(runhp[mt][r], __shfl_xor(runhp[mt][r], o, 16));
                runhn[mt][r] = fminf(runhn[mt][r], __shfl_xor(runhn[mt][r], o, 16));
            }
        }

    if (m16 == 0) {
        #pragma unroll
        for (int mt = 0; mt < 2; ++mt)
            #pragma unroll
            for (int r = 0; r < 4; ++r) {
                int row = rbase + mt * 16 + quad * 4 + r;
                float sqa = sq[row];
                float d2p = fmaxf(sqa + runhp[mt][r], 0.0f);  // == ref's max(d2,0)
                float d2n = fmaxf(sqa + runhn[mt][r], 0.0f);
                atomicMax(&hp_bits[row], __float_as_uint(d2p));
                atomicMax(&hn_comp[row], ~__float_as_uint(d2n));  // min via complement
            }
    }
}

// Kernel 3: per-row loss + grid reduction; last block writes the scalar.
__global__ void finalize_kernel(const unsigned* __restrict__ hp_bits,
                                const unsigned* __restrict__ hn_comp,
                                const int* __restrict__ lab,
                                const unsigned* __restrict__ hist,
                                float* __restrict__ gsum, float* __restrict__ gcnt,
                                unsigned* __restrict__ bcount,
                                float* __restrict__ out, int N)
{
    __shared__ float s_sum[256];
    __shared__ float s_cnt[256];
    int tid = threadIdx.x;
    int row = blockIdx.x * 256 + tid;
    float loss = 0.0f, cv = 0.0f;
    if (row < N) {
        unsigned c = hist[lab[row]];
        bool valid = (c >= 2u) && (c < (unsigned)N);
        if (valid) {
            float dp = sqrtf(__uint_as_float(hp_bits[row]));
            float dn = sqrtf(__uint_as_float(~hn_comp[row]));
            loss = fmaxf(dp - dn + MARGIN, 0.0f);
            cv = 1.0f;
        }
    }
    s_sum[tid] = loss; s_cnt[tid] = cv;
    __syncthreads();
    for (int o = 128; o > 0; o >>= 1) {
        if (tid < o) { s_sum[tid] += s_sum[tid + o]; s_cnt[tid] += s_cnt[tid + o]; }
        __syncthreads();
    }
    if (tid == 0) {
        atomicAdd(gsum, s_sum[0]);
        atomicAdd(gcnt, s_cnt[0]);
        __threadfence();
        unsigned old = atomicAdd(bcount, 1u);
        if (old == gridDim.x - 1) {
            float s = atomicAdd(gsum, 0.0f);   // coherent read
            float c = atomicAdd(gcnt, 0.0f);
            out[0] = (c > 0.0f) ? s / c : 0.0f;
        }
    }
}

extern "C" void kernel_launch(void* const* d_in, const int* in_sizes, int n_in,
                              void* d_out, int out_size, void* d_ws, size_t ws_size,
                              hipStream_t stream) {
    const float* x = (const float*)d_in[0];
    const int* lab = (const int*)d_in[1];
    float* out = (float*)d_out;
    const int N = in_sizes[1];          // 8192

    unsigned* ws = (unsigned*)d_ws;
    unsigned* hist    = ws + WS_HIST;
    unsigned* scal    = ws + WS_GSUM;   // gsum, gcnt, bcount, pad
    float* gsum = (float*)(ws + WS_GSUM);
    float* gcnt = (float*)(ws + WS_GCNT);
    unsigned* bcount = ws + WS_BCNT;
    unsigned* hp_bits = ws + WS_HP;
    unsigned* hn_comp = ws + WS_HN;
    float* sq = (float*)(ws + WS_SQ);
    ushort* xs = (ushort*)(ws + WS_XB);

    prep_kernel<<<N / 32, 256, 0, stream>>>(x, xs, sq, hist, scal, hp_bits, hn_comp, N);
    dim3 grid(N / 128, NSPLIT);
    tile_kernel<<<grid, 256, 0, stream>>>(xs, sq, lab, hist, hp_bits, hn_comp, N);
    finalize_kernel<<<N / 256, 256, 0, stream>>>(hp_bits, hn_comp, lab, hist,
                                                 gsum, gcnt, bcount, out, N);
}